// Round 1
// baseline (307.993 us; speedup 1.0000x reference)
//
#include <hip/hip_runtime.h>
#include <hip/hip_bf16.h>
#include <cstdint>

#define TOKENS 8192
#define DIN 1024
#define DOUT 1024
#define NE 8

typedef __bf16 bf16;
typedef __attribute__((ext_vector_type(8))) __bf16 bf16x8;
typedef __attribute__((ext_vector_type(4))) float floatx4;

// async global->LDS, 16B per lane. LDS dest must be wave-uniform base + lane*16.
__device__ __forceinline__ void async16(const void* gptr, void* lptr) {
  __builtin_amdgcn_global_load_lds(
      (const __attribute__((address_space(1))) void*)gptr,
      (__attribute__((address_space(3))) void*)lptr,
      16, 0, 0);
}

// ---------------------------------------------------------------------------
// Kernel 1: gate softmax (fp32) + x -> bf16 conversion.
// One wave per token. grid = 8192/4 blocks x 256 threads.
// ---------------------------------------------------------------------------
__global__ __launch_bounds__(256) void gate_kernel(
    const float* __restrict__ x, const float* __restrict__ gw,
    const float* __restrict__ gb, float* __restrict__ g,
    bf16* __restrict__ xb) {
  const int lane = threadIdx.x & 63;
  const int wave = threadIdx.x >> 6;
  const int t = blockIdx.x * 4 + wave;
  const float* xr = x + (size_t)t * DIN;
  bf16* xbr = xb + (size_t)t * DIN;

  float acc[NE];
#pragma unroll
  for (int e = 0; e < NE; ++e) acc[e] = 0.f;

#pragma unroll
  for (int it = 0; it < 4; ++it) {
    const int i = it * 256 + lane * 4;
    const floatx4 xv = *(const floatx4*)(xr + i);
    union { bf16 b[4]; uint64_t u; } cv;
#pragma unroll
    for (int j = 0; j < 4; ++j) cv.b[j] = (bf16)xv[j];
    *(uint64_t*)(xbr + i) = cv.u;
#pragma unroll
    for (int j = 0; j < 4; ++j) {
      const floatx4 w0 = *(const floatx4*)(gw + (size_t)(i + j) * NE);
      const floatx4 w1 = *(const floatx4*)(gw + (size_t)(i + j) * NE + 4);
      const float xs = xv[j];
#pragma unroll
      for (int e = 0; e < 4; ++e) {
        acc[e]     += xs * w0[e];
        acc[e + 4] += xs * w1[e];
      }
    }
  }
  // wave-64 butterfly reduce each of the 8 logits
#pragma unroll
  for (int e = 0; e < NE; ++e) {
#pragma unroll
    for (int off = 32; off > 0; off >>= 1)
      acc[e] += __shfl_xor(acc[e], off, 64);
  }
  // softmax (redundant on all lanes; lane 0 stores)
  float lg[NE];
  float mx = -3.0e38f;
#pragma unroll
  for (int e = 0; e < NE; ++e) { lg[e] = acc[e] + gb[e]; mx = fmaxf(mx, lg[e]); }
  float s = 0.f;
#pragma unroll
  for (int e = 0; e < NE; ++e) { lg[e] = __expf(lg[e] - mx); s += lg[e]; }
  const float inv = 1.f / s;
  if (lane == 0) {
    floatx4 o0, o1;
#pragma unroll
    for (int e = 0; e < 4; ++e) { o0[e] = lg[e] * inv; o1[e] = lg[e + 4] * inv; }
    *(floatx4*)(g + (size_t)t * NE) = o0;
    *(floatx4*)(g + (size_t)t * NE + 4) = o1;
  }
}

// ---------------------------------------------------------------------------
// Kernel 2: W[e][i][o] fp32  ->  Wt[e][o][i] bf16  (transpose to B^T layout)
// 32x32 tiles, block (32,8), grid (32,32,8).
// ---------------------------------------------------------------------------
__global__ __launch_bounds__(256) void wt_kernel(
    const float* __restrict__ w, bf16* __restrict__ wt) {
  __shared__ float tile[32][33];
  const int e = blockIdx.z;
  const int i0 = blockIdx.y * 32;
  const int o0 = blockIdx.x * 32;
  const int tx = threadIdx.x;  // 0..31
  const int ty = threadIdx.y;  // 0..7

  const float* src = w + ((size_t)e * DIN + i0) * DOUT + o0;
#pragma unroll
  for (int r = ty; r < 32; r += 8) tile[r][tx] = src[(size_t)r * DOUT + tx];
  __syncthreads();
  bf16* dst = wt + ((size_t)e * DOUT + o0) * DIN + i0;
#pragma unroll
  for (int r = ty; r < 32; r += 8) dst[(size_t)r * DIN + tx] = (bf16)tile[tx][r];
}

// ---------------------------------------------------------------------------
// Kernel 3: fused MoE GEMM.
// out[t,o] = sum_e g[t,e] * (x @ W_e)[t,o]
// m97 structure: BM=BN=128, BK=32, 256 threads (4 waves, each 64x64 = 4x4 of
// 16x16x32 bf16 MFMA), global_load_lds width=16, expert loop outer with fp32
// gate fold into a second accumulator.
// grid = (8192/128)*(1024/128) = 512 blocks.
// ---------------------------------------------------------------------------
__global__ __launch_bounds__(256, 2) void moe_gemm(
    const bf16* __restrict__ xb, const bf16* __restrict__ wt,
    const float* __restrict__ g, float* __restrict__ out) {
  __shared__ __align__(16) bf16 As[128 * 32];  // [m][k] row-major, 8KB
  __shared__ __align__(16) bf16 Bs[128 * 32];  // [n][k] row-major, 8KB

  const int tid = threadIdx.x;
  const int bm = blockIdx.x >> 3;  // 64 token tiles
  const int bn = blockIdx.x & 7;   // 8 out tiles
  const int lane = tid & 63;
  const int wave = tid >> 6;
  const int wm = wave >> 1, wn = wave & 1;
  const int lr = lane & 15, lq = lane >> 4;

  // staging map: thread tid covers LDS elems [tid*8, tid*8+8) (j=0) and
  // +2048 (j=1); row = tid/4 (+64), col = (tid%4)*8  -> lane-contiguous.
  const int srow = tid >> 2;
  const int scol = (tid & 3) * 8;

  const bf16* agp = xb + ((size_t)(bm * 128 + srow)) * DIN + scol;
  bf16* const alp = As + tid * 8;
  bf16* const blp = Bs + tid * 8;

  const floatx4 fzero = {0.f, 0.f, 0.f, 0.f};
  floatx4 accF[4][4];
#pragma unroll
  for (int im = 0; im < 4; ++im)
#pragma unroll
    for (int in = 0; in < 4; ++in) accF[im][in] = fzero;

  const int tok0 = bm * 128 + wm * 64;

  for (int e = 0; e < NE; ++e) {
    const bf16* bgp = wt + ((size_t)e << 20) +
                      ((size_t)(bn * 128 + srow)) * DIN + scol;
    floatx4 accE[4][4];
#pragma unroll
    for (int im = 0; im < 4; ++im)
#pragma unroll
      for (int in = 0; in < 4; ++in) accE[im][in] = fzero;

    for (int k0 = 0; k0 < DIN; k0 += 32) {
      __syncthreads();  // protect LDS from previous iteration's readers
      async16(agp + k0, alp);
      async16(agp + (size_t)64 * DIN + k0, alp + 2048);
      async16(bgp + k0, blp);
      async16(bgp + (size_t)64 * DIN + k0, blp + 2048);
      __syncthreads();  // drains vmcnt before barrier

      bf16x8 av[4], bv[4];
#pragma unroll
      for (int im = 0; im < 4; ++im)
        av[im] = *(const bf16x8*)(As + (wm * 64 + im * 16 + lr) * 32 + lq * 8);
#pragma unroll
      for (int in = 0; in < 4; ++in)
        bv[in] = *(const bf16x8*)(Bs + (wn * 64 + in * 16 + lr) * 32 + lq * 8);
#pragma unroll
      for (int im = 0; im < 4; ++im)
#pragma unroll
        for (int in = 0; in < 4; ++in)
          accE[im][in] = __builtin_amdgcn_mfma_f32_16x16x32_bf16(
              av[im], bv[in], accE[im][in], 0, 0, 0);
    }

    // fold: accF += g[row, e] * accE   (fp32; C/D row = lq*4 + r, col = lr)
#pragma unroll
    for (int im = 0; im < 4; ++im) {
      float gv[4];
#pragma unroll
      for (int r = 0; r < 4; ++r)
        gv[r] = g[(size_t)(tok0 + im * 16 + lq * 4 + r) * NE + e];
#pragma unroll
      for (int in = 0; in < 4; ++in)
#pragma unroll
        for (int r = 0; r < 4; ++r)
          accF[im][in][r] += gv[r] * accE[im][in][r];
    }
  }

  // epilogue: scalar stores, 16 lanes consecutive in col
#pragma unroll
  for (int im = 0; im < 4; ++im)
#pragma unroll
    for (int in = 0; in < 4; ++in) {
      const int col = bn * 128 + wn * 64 + in * 16 + lr;
#pragma unroll
      for (int r = 0; r < 4; ++r)
        out[(size_t)(tok0 + im * 16 + lq * 4 + r) * DOUT + col] =
            accF[im][in][r];
    }
}

// ---------------------------------------------------------------------------
extern "C" void kernel_launch(void* const* d_in, const int* in_sizes, int n_in,
                              void* d_out, int out_size, void* d_ws,
                              size_t ws_size, hipStream_t stream) {
  const float* x  = (const float*)d_in[0];  // [4,2048,1024]
  const float* gw = (const float*)d_in[1];  // [1024,8]
  const float* gb = (const float*)d_in[2];  // [8]
  const float* w  = (const float*)d_in[3];  // [8,1024,1024]
  float* out = (float*)d_out;               // [4,2048,1024]

  char* ws = (char*)d_ws;
  float* g  = (float*)ws;                                   // 256 KiB
  bf16* xb  = (bf16*)(ws + 262144);                         // 16 MiB
  bf16* wt  = (bf16*)(ws + 262144 + (size_t)TOKENS * DIN * 2);  // 16 MiB

  gate_kernel<<<TOKENS / 4, 256, 0, stream>>>(x, gw, gb, g, xb);
  dim3 wtg(DOUT / 32, DIN / 32, NE);
  dim3 wtb(32, 8);
  wt_kernel<<<wtg, wtb, 0, stream>>>(w, wt);
  moe_gemm<<<512, 256, 0, stream>>>(xb, wt, g, out);
}

// Round 2
// 284.132 us; speedup vs baseline: 1.0840x; 1.0840x over previous
//
#include <hip/hip_runtime.h>
#include <hip/hip_bf16.h>
#include <cstdint>

#define TOKENS 8192
#define DIN 1024
#define DOUT 1024
#define NE 8

typedef __bf16 bf16;
typedef __attribute__((ext_vector_type(8))) __bf16 bf16x8;
typedef __attribute__((ext_vector_type(4))) float floatx4;
typedef __attribute__((ext_vector_type(2))) float floatx2;

// async global->LDS, 16B per lane. LDS dest must be wave-uniform base + lane*16.
__device__ __forceinline__ void async16(const void* gptr, void* lptr) {
  __builtin_amdgcn_global_load_lds(
      (const __attribute__((address_space(1))) void*)gptr,
      (__attribute__((address_space(3))) void*)lptr,
      16, 0, 0);
}

// ---------------------------------------------------------------------------
// Kernel 1: gate softmax (fp32) + x -> bf16 conversion.
// One wave per token; lane L handles rows {2L, 2L+1} per iter so gw loads are
// 64B/lane fully coalesced (was: 128B lane stride -> scattered 16B loads).
// ---------------------------------------------------------------------------
__global__ __launch_bounds__(256) void gate_kernel(
    const float* __restrict__ x, const float* __restrict__ gw,
    const float* __restrict__ gb, float* __restrict__ g,
    bf16* __restrict__ xb) {
  const int lane = threadIdx.x & 63;
  const int wave = threadIdx.x >> 6;
  const int t = blockIdx.x * 4 + wave;
  const float* xr = x + (size_t)t * DIN;
  bf16* xbr = xb + (size_t)t * DIN;

  float acc[NE];
#pragma unroll
  for (int e = 0; e < NE; ++e) acc[e] = 0.f;

#pragma unroll
  for (int it = 0; it < 8; ++it) {
    const int i = it * 128 + lane * 2;  // rows i, i+1
    const floatx2 xv = *(const floatx2*)(xr + i);
    union { bf16 b[2]; uint32_t u; } cv;
    cv.b[0] = (bf16)xv[0]; cv.b[1] = (bf16)xv[1];
    *(uint32_t*)(xbr + i) = cv.u;
    const floatx4 w00 = *(const floatx4*)(gw + (size_t)i * NE);
    const floatx4 w01 = *(const floatx4*)(gw + (size_t)i * NE + 4);
    const floatx4 w10 = *(const floatx4*)(gw + (size_t)(i + 1) * NE);
    const floatx4 w11 = *(const floatx4*)(gw + (size_t)(i + 1) * NE + 4);
#pragma unroll
    for (int e = 0; e < 4; ++e) {
      acc[e]     += xv[0] * w00[e] + xv[1] * w10[e];
      acc[e + 4] += xv[0] * w01[e] + xv[1] * w11[e];
    }
  }
#pragma unroll
  for (int e = 0; e < NE; ++e) {
#pragma unroll
    for (int off = 32; off > 0; off >>= 1)
      acc[e] += __shfl_xor(acc[e], off, 64);
  }
  float lg[NE];
  float mx = -3.0e38f;
#pragma unroll
  for (int e = 0; e < NE; ++e) { lg[e] = acc[e] + gb[e]; mx = fmaxf(mx, lg[e]); }
  float s = 0.f;
#pragma unroll
  for (int e = 0; e < NE; ++e) { lg[e] = __expf(lg[e] - mx); s += lg[e]; }
  const float inv = 1.f / s;
  if (lane == 0) {
    floatx4 o0, o1;
#pragma unroll
    for (int e = 0; e < 4; ++e) { o0[e] = lg[e] * inv; o1[e] = lg[e + 4] * inv; }
    *(floatx4*)(g + (size_t)t * NE) = o0;
    *(floatx4*)(g + (size_t)t * NE + 4) = o1;
  }
}

// ---------------------------------------------------------------------------
// Kernel 2: W[e][i][o] fp32 -> Wt[e][o][i] bf16. 64x64 tiles, 256 threads,
// float4 loads / 8B bf16 stores. LDS stride 65 floats: bank=(r+c)%32, <=2-way.
// grid (16,16,8) = 2048 blocks.
// ---------------------------------------------------------------------------
__global__ __launch_bounds__(256) void wt_kernel(
    const float* __restrict__ w, bf16* __restrict__ wt) {
  __shared__ float tile[64][65];
  const int e = blockIdx.z;
  const int i0 = blockIdx.y * 64;
  const int o0 = blockIdx.x * 64;
  const int tid = threadIdx.x;
  const int c4 = (tid & 15) * 4;
  const int r = tid >> 4;  // 0..15

  const float* src = w + ((size_t)e * DIN + i0) * DOUT + o0;
#pragma unroll
  for (int rr = r; rr < 64; rr += 16) {
    const floatx4 v = *(const floatx4*)(src + (size_t)rr * DOUT + c4);
    tile[rr][c4] = v[0]; tile[rr][c4 + 1] = v[1];
    tile[rr][c4 + 2] = v[2]; tile[rr][c4 + 3] = v[3];
  }
  __syncthreads();
  bf16* dst = wt + ((size_t)e * DOUT + o0) * DIN + i0;
#pragma unroll
  for (int rr = r; rr < 64; rr += 16) {  // rr = output row (o), c4 = i cols
    union { bf16 b[4]; uint64_t u; } cv;
#pragma unroll
    for (int j = 0; j < 4; ++j) cv.b[j] = (bf16)tile[c4 + j][rr];
    *(uint64_t*)(dst + (size_t)rr * DIN + c4) = cv.u;
  }
}

// ---------------------------------------------------------------------------
// Kernel 3: fused MoE GEMM (m97 structure + XOR-swizzled LDS).
// Swizzle: physical 16B-unit of logical (row, kg) = row*4 + (kg ^ ((row>>1)&3)).
// Read-side bank group = (row&1)*4 + (lq^((row>>1)&3)): rows r..r+7 hit all 8
// groups, +8 repeats -> 2-way (free, m136). Staging keeps LDS dest = tid*16
// (global_load_lds-legal); the *global* column is permuted instead, which only
// permutes lanes within a 64B span -> coalescing preserved. Row+64 half has
// the same phase (64>>1 = 32 === 0 mod 4) so one scol serves both async16s.
// ---------------------------------------------------------------------------
__global__ __launch_bounds__(256, 2) void moe_gemm(
    const bf16* __restrict__ xb, const bf16* __restrict__ wt,
    const float* __restrict__ g, float* __restrict__ out) {
  __shared__ __align__(16) bf16 As[128 * 32];
  __shared__ __align__(16) bf16 Bs[128 * 32];

  const int tid = threadIdx.x;
  const int bm = blockIdx.x >> 3;
  const int bn = blockIdx.x & 7;
  const int lane = tid & 63;
  const int wave = tid >> 6;
  const int wm = wave >> 1, wn = wave & 1;
  const int lr = lane & 15, lq = lane >> 4;

  const int srow = tid >> 2;
  const int scol = (((tid & 3) ^ ((tid >> 3) & 3)) << 3);  // swizzled k-group

  const bf16* agp = xb + ((size_t)(bm * 128 + srow)) * DIN + scol;
  bf16* const alp = As + tid * 8;
  bf16* const blp = Bs + tid * 8;

  // fragment read offset: row*32 + (lq ^ ((lr>>1)&3))*8   (row base mult of 16)
  const int kgp = ((lq ^ ((lr >> 1) & 3)) << 3);

  const floatx4 fzero = {0.f, 0.f, 0.f, 0.f};
  floatx4 accF[4][4];
#pragma unroll
  for (int im = 0; im < 4; ++im)
#pragma unroll
    for (int in = 0; in < 4; ++in) accF[im][in] = fzero;

  const int tok0 = bm * 128 + wm * 64;

  for (int e = 0; e < NE; ++e) {
    const bf16* bgp = wt + ((size_t)e << 20) +
                      ((size_t)(bn * 128 + srow)) * DIN + scol;
    floatx4 accE[4][4];
#pragma unroll
    for (int im = 0; im < 4; ++im)
#pragma unroll
      for (int in = 0; in < 4; ++in) accE[im][in] = fzero;

    for (int k0 = 0; k0 < DIN; k0 += 32) {
      __syncthreads();
      async16(agp + k0, alp);
      async16(agp + (size_t)64 * DIN + k0, alp + 2048);
      async16(bgp + k0, blp);
      async16(bgp + (size_t)64 * DIN + k0, blp + 2048);
      __syncthreads();

      bf16x8 av[4], bv[4];
#pragma unroll
      for (int im = 0; im < 4; ++im)
        av[im] = *(const bf16x8*)(As + (wm * 64 + im * 16 + lr) * 32 + kgp);
#pragma unroll
      for (int in = 0; in < 4; ++in)
        bv[in] = *(const bf16x8*)(Bs + (wn * 64 + in * 16 + lr) * 32 + kgp);
#pragma unroll
      for (int im = 0; im < 4; ++im)
#pragma unroll
        for (int in = 0; in < 4; ++in)
          accE[im][in] = __builtin_amdgcn_mfma_f32_16x16x32_bf16(
              av[im], bv[in], accE[im][in], 0, 0, 0);
    }

#pragma unroll
    for (int im = 0; im < 4; ++im) {
      float gv[4];
#pragma unroll
      for (int r = 0; r < 4; ++r)
        gv[r] = g[(size_t)(tok0 + im * 16 + lq * 4 + r) * NE + e];
#pragma unroll
      for (int in = 0; in < 4; ++in)
#pragma unroll
        for (int r = 0; r < 4; ++r)
          accF[im][in][r] += gv[r] * accE[im][in][r];
    }
  }

#pragma unroll
  for (int im = 0; im < 4; ++im)
#pragma unroll
    for (int in = 0; in < 4; ++in) {
      const int col = bn * 128 + wn * 64 + in * 16 + lr;
#pragma unroll
      for (int r = 0; r < 4; ++r)
        out[(size_t)(tok0 + im * 16 + lq * 4 + r) * DOUT + col] =
            accF[im][in][r];
    }
}

// ---------------------------------------------------------------------------
extern "C" void kernel_launch(void* const* d_in, const int* in_sizes, int n_in,
                              void* d_out, int out_size, void* d_ws,
                              size_t ws_size, hipStream_t stream) {
  const float* x  = (const float*)d_in[0];
  const float* gw = (const float*)d_in[1];
  const float* gb = (const float*)d_in[2];
  const float* w  = (const float*)d_in[3];
  float* out = (float*)d_out;

  char* ws = (char*)d_ws;
  float* g  = (float*)ws;
  bf16* xb  = (bf16*)(ws + 262144);
  bf16* wt  = (bf16*)(ws + 262144 + (size_t)TOKENS * DIN * 2);

  gate_kernel<<<TOKENS / 4, 256, 0, stream>>>(x, gw, gb, g, xb);
  dim3 wtg(DOUT / 64, DIN / 64, NE);
  wt_kernel<<<wtg, 256, 0, stream>>>(w, wt);
  moe_gemm<<<512, 256, 0, stream>>>(xb, wt, g, out);
}